// Round 5
// baseline (2170.003 us; speedup 1.0000x reference)
//
#include <hip/hip_runtime.h>
#include <stdint.h>

// Problem constants
#define NB   131072
#define DIN  128
#define HD   256
#define VT   6
#define TS   6
// Tiling: BM=32 rows/block, 256 threads = 4 waves (wave owns 64 weight-cols),
// 2 blocks/CU. MFMA 16x16x32 bf16; fp32 exact via 3-plane bf16 split (6 products).
// This revision: software-pipelined gemm_pass (prefetch next (kc,mtl) A-frags
// and next-kc B-frags one step ahead) to hide L2/LDS latency under the MFMA
// burst. MFMA order identical to the serial version -> bit-exact outputs.
// (Resubmission of Round-3 source: bench infra failed before measuring it.)
#define BM   32
#define NTH  256

typedef __attribute__((ext_vector_type(8))) short bfrag;   // 8 bf16 (4 VGPRs)
typedef __attribute__((ext_vector_type(4))) short bh4;     // 4 bf16
typedef __attribute__((ext_vector_type(4))) float f32x4;   // MFMA C/D

struct Keys { uint32_t a[6]; uint32_t b[6]; };

// hp plane layout: [p][kc][nt 2][lane 64][8] shorts, +16-short pad per (p,kc) block.
#define HPS(p, kc, nt, lp, j) ((((p) * 8 + (kc)) * 1040) + (nt) * 512 + (lp) * 8 + (j))

// ---- JAX threefry2x32 (20 rounds), bit-exact ----
__host__ __device__ inline void tf2x32(uint32_t k0, uint32_t k1,
                                       uint32_t c0, uint32_t c1,
                                       uint32_t& o0, uint32_t& o1) {
  uint32_t ks2 = k0 ^ k1 ^ 0x1BD11BDAu;
  uint32_t x0 = c0 + k0, x1 = c1 + k1;
#define TFR(d) { x0 += x1; x1 = (x1 << (d)) | (x1 >> (32 - (d))); x1 ^= x0; }
  TFR(13) TFR(15) TFR(26) TFR(6)
  x0 += k1;  x1 += ks2 + 1u;
  TFR(17) TFR(29) TFR(16) TFR(24)
  x0 += ks2; x1 += k0 + 2u;
  TFR(13) TFR(15) TFR(26) TFR(6)
  x0 += k0;  x1 += k1 + 3u;
  TFR(17) TFR(29) TFR(16) TFR(24)
  x0 += k1;  x1 += ks2 + 4u;
  TFR(13) TFR(15) TFR(26) TFR(6)
  x0 += ks2; x1 += k0 + 5u;
#undef TFR
  o0 = x0; o1 = x1;
}

__device__ __forceinline__ unsigned short f2bf(float x) {   // RNE f32->bf16
  uint32_t b = __float_as_uint(x);
  uint32_t r = b + 0x7FFFu + ((b >> 16) & 1u);
  return (unsigned short)(r >> 16);
}
__device__ __forceinline__ float bf2f(unsigned short u) {
  return __uint_as_float(((uint32_t)u) << 16);
}
__device__ __forceinline__ float sigf(float v) { return 1.0f / (1.0f + expf(-v)); }

#define MFMA16(a, b, c) __builtin_amdgcn_mfma_f32_16x16x32_bf16((a), (b), (c), 0, 0, 0)

// 6-product bf16x3: (hi,hi),(hi,mid),(mid,hi),(mid,mid),(hi,lo),(lo,hi)
__device__ __forceinline__ f32x4 prod6(const bfrag A[3], bfrag B0, bfrag B1, bfrag B2,
                                       f32x4 c) {
  c = MFMA16(A[0], B0, c);
  c = MFMA16(A[0], B1, c);
  c = MFMA16(A[1], B0, c);
  c = MFMA16(A[1], B1, c);
  c = MFMA16(A[0], B2, c);
  c = MFMA16(A[2], B0, c);
  return c;
}

// ---- Kernel A: pre tables (gate bias folded), W frags, W_out frags ----
// A-layout: ((p*KC + kc)*16 + mt)*512 + lane*8 + j holds
// A[m = mt*16 + (lane&15)][k = kc*32 + (lane>>4)*8 + j] = W[krow0+k][m].
__global__ void pre_kernel(const float* __restrict__ W_enc,
                           const float* __restrict__ W_embed,
                           const float* __restrict__ b_embed,
                           const float* __restrict__ start_embed,
                           const float* __restrict__ W_z, const float* __restrict__ b_z,
                           const float* __restrict__ W_r, const float* __restrict__ b_r,
                           const float* __restrict__ W_h, const float* __restrict__ b_h,
                           const float* __restrict__ W_out,
                           float* __restrict__ pre,
                           unsigned short* __restrict__ encf,
                           unsigned short* __restrict__ zf,
                           unsigned short* __restrict__ rf,
                           unsigned short* __restrict__ hf,
                           unsigned short* __restrict__ woutf) {
  const int bid = blockIdx.x;
  if (bid < 24) {  // pre tables: codes 0..5 = W_embed[c]+b_embed, 6 = b_embed, 7 = start
    __shared__ float xin[HD];
    const int c = bid & 7, g = bid >> 3, j = threadIdx.x;
    float v;
    if (c < 6)       v = W_embed[c * HD + j] + b_embed[j];
    else if (c == 6) v = b_embed[j];
    else             v = start_embed[j];
    xin[j] = v;
    __syncthreads();
    const float* Wg = (g == 0) ? W_z : (g == 1) ? W_r : W_h;  // top half rows 0..255
    const float* bg = (g == 0) ? b_z : (g == 1) ? b_r : b_h;
    float acc = bg[j];                       // fold gate bias into pre table
    for (int k = 0; k < HD; ++k) acc += xin[k] * Wg[k * HD + j];
    pre[(g * 8 + c) * HD + j] = acc;
    return;
  }
  if (bid >= 136) {  // W_out frags: single mt, KC=8; A[m][k] = W_out[k][m] (m<6)
    int id2 = (bid - 136) * 256 + threadIdx.x;   // 0..511
    int kc = id2 >> 6, lane = id2 & 63;
    int m = lane & 15, k0 = kc * 32 + ((lane >> 4) & 3) * 8;
    __align__(16) unsigned short P[3][8];
#pragma unroll
    for (int j = 0; j < 8; ++j) {
      float w = (m < VT) ? W_out[(size_t)(k0 + j) * VT + m] : 0.f;
      unsigned short h1 = f2bf(w);  float r1 = w - bf2f(h1);
      unsigned short h2 = f2bf(r1); float r2 = r1 - bf2f(h2);
      P[0][j] = h1; P[1][j] = h2; P[2][j] = f2bf(r2);
    }
    for (int p = 0; p < 3; ++p) {
      unsigned short* d = woutf + ((size_t)(p * 8 + kc) * 512) + (size_t)lane * 8;
      *(uint4*)d = *(const uint4*)P[p];
    }
    return;
  }
  int id = (bid - 24) * 256 + threadIdx.x;   // 0 .. 28671
  const float* src; unsigned short* dst; int kc, mt, lane, KC, krow0;
  if (id < 4096) {            // encoder frags: KC=4 (K=128)
    lane = id & 63; mt = (id >> 6) & 15; kc = id >> 10;
    src = W_enc; dst = encf; KC = 4; krow0 = 0;
  } else {                    // gate frags: KC=8 (K=256), bottom half rows 256..511
    int rem = id - 4096; int g = rem >> 13; int rr = rem & 8191;
    lane = rr & 63; mt = (rr >> 6) & 15; kc = rr >> 10;
    src = (g == 0) ? W_z : (g == 1) ? W_r : W_h;
    dst = (g == 0) ? zf  : (g == 1) ? rf  : hf;
    KC = 8; krow0 = 256;
  }
  const int m  = mt * 16 + (lane & 15);
  const int k0 = kc * 32 + ((lane >> 4) & 3) * 8;
  __align__(16) unsigned short P[3][8];
#pragma unroll
  for (int j = 0; j < 8; ++j) {
    float w = src[(size_t)(krow0 + k0 + j) * HD + m];
    unsigned short h1 = f2bf(w);  float r1 = w - bf2f(h1);
    unsigned short h2 = f2bf(r1); float r2 = r1 - bf2f(h2);
    P[0][j] = h1; P[1][j] = h2; P[2][j] = f2bf(r2);   // hi+mid+lo == w exactly
  }
  for (int p = 0; p < 3; ++p) {
    unsigned short* d = dst + ((size_t)(p * KC + kc) * 16 + mt) * 512 + (size_t)lane * 8;
    *(uint4*)d = *(const uint4*)P[p];
  }
}

// GEMM pass, software-pipelined: A = W frags (global/L2), B = h planes (LDS).
// Wave owns mt = wave*4 + mtl. NG=2 shares B across two A streams (z+r fused).
// Prefetch depth 1 at (kc,mtl) granularity for A, kc granularity for B: the
// ~200-300 cyc L2 latency of the next A-frags hides under the current 12-24
// MFMAs (~230-460 cyc). MFMA order is IDENTICAL to the serial version.
template<int KC, int NG>
__device__ __forceinline__ void gemm_pass(const unsigned short* __restrict__ f0,
                                          const unsigned short* __restrict__ f1,
                                          const unsigned short* hp_s,
                                          int wave, int lane,
                                          f32x4 acc0[4][2], f32x4 acc1[4][2]) {
  const int mbase = wave * 4;

  auto loadA = [&](bfrag A0[3], bfrag A1[3], int kc, int mtl) {
    const int fo = (kc * 16 + mbase + mtl) * 512 + lane * 8;
#pragma unroll
    for (int p = 0; p < 3; ++p) A0[p] = *(const bfrag*)(f0 + fo + p * (KC * 8192));
    if (NG == 2) {
#pragma unroll
      for (int p = 0; p < 3; ++p) A1[p] = *(const bfrag*)(f1 + fo + p * (KC * 8192));
    }
  };
  auto loadB = [&](bfrag B[3][2], int kc) {
#pragma unroll
    for (int p = 0; p < 3; ++p)
#pragma unroll
      for (int nt = 0; nt < 2; ++nt)
        B[p][nt] = *(const bfrag*)&hp_s[HPS(p, kc, nt, lane, 0)];
  };

  bfrag Ac0[3], Ac1[3], An0[3], An1[3];
  bfrag Bc[3][2], Bn[3][2];
  loadB(Bc, 0);
  loadA(Ac0, Ac1, 0, 0);
#pragma unroll 1
  for (int kc = 0; kc < KC; ++kc) {
#pragma unroll
    for (int mtl = 0; mtl < 4; ++mtl) {
      // ---- prefetch next operands (stay in flight across the MFMAs) ----
      if (mtl < 3) {
        loadA(An0, An1, kc, mtl + 1);
      } else if (kc + 1 < KC) {
        loadB(Bn, kc + 1);
        loadA(An0, An1, kc + 1, 0);
      }
      // ---- compute with current ----
#pragma unroll
      for (int nt = 0; nt < 2; ++nt) {
        acc0[mtl][nt] = prod6(Ac0, Bc[0][nt], Bc[1][nt], Bc[2][nt], acc0[mtl][nt]);
        if (NG == 2)
          acc1[mtl][nt] = prod6(Ac1, Bc[0][nt], Bc[1][nt], Bc[2][nt], acc1[mtl][nt]);
      }
      // ---- rotate buffers (mtl fully unrolled -> SSA renaming, no movs) ----
#pragma unroll
      for (int p = 0; p < 3; ++p) {
        Ac0[p] = An0[p];
        if (NG == 2) Ac1[p] = An1[p];
      }
      if (mtl == 3) {
#pragma unroll
        for (int p = 0; p < 3; ++p)
#pragma unroll
          for (int nt = 0; nt < 2; ++nt) Bc[p][nt] = Bn[p][nt];
      }
    }
  }
}

// gumbel batch for step s, tile (16 rows), into double-buffered LDS
__device__ __forceinline__ void gen_gumbel(float* __restrict__ gmb, int s, int b0,
                                           int tile, int lane,
                                           uint32_t ka, uint32_t kb) {
  uint32_t basej = (uint32_t)(b0 + tile * 16) * 6u;
#pragma unroll
  for (int rep = 0; rep < 2; ++rep) {
    int d = rep * 64 + lane;
    if (d < 96) {
      uint32_t o0, o1;
      tf2x32(ka, kb, 0u, basej + (uint32_t)d, o0, o1);
      uint32_t bits = o0 ^ o1;
      float f = __uint_as_float((bits >> 9) | 0x3f800000u) - 1.0f;
      float u = (f > 0.f) ? f : 1.175494350822288e-38f;
      float lg1 = (float)log((double)u);
      float lg2 = (float)log((double)(-lg1));
      gmb[((s & 1) * 32 + tile * 16 + d / 6) * 6 + (d % 6)] = -lg2;
    }
  }
}

// ---- main kernel: persistent rollout; h_old in registers; logits via MFMA;
// gumbels generated by waves 2-3 overlapped with waves 0-1's logits GEMM.
__launch_bounds__(NTH, 2)
__global__ void main_kernel(const float* __restrict__ x,
                            const float* __restrict__ b_enc,
                            const float* __restrict__ b_out,
                            const float* __restrict__ pre,
                            const unsigned short* __restrict__ encf,
                            const unsigned short* __restrict__ zf,
                            const unsigned short* __restrict__ rf,
                            const unsigned short* __restrict__ hf,
                            const unsigned short* __restrict__ woutf,
                            float* __restrict__ out, Keys keys) {
  __shared__ __align__(16) unsigned short hp_s[3 * 8 * 1040];  // 49,920 B
  __shared__ float gmb_s[2 * 32 * 6];                          //  1,536 B
  __shared__ float boutL[16];
  __shared__ unsigned state[BM];
  __shared__ float tlp[BM];
  // total ~51.8 KB -> 2 blocks/CU

  const int tid = threadIdx.x;
  const int wave = tid >> 6, lane = tid & 63;
  const int ln = lane & 15, qk = lane >> 4;
  const int b0 = blockIdx.x * BM;

  if (tid < 16) boutL[tid] = (tid < VT) ? b_out[tid] : 0.f;
  if (tid < BM) { state[tid] = 7u; tlp[tid] = 0.f; }

  // stage x (B-operand planes), kc 0..3
  for (int i = tid; i < BM * DIN; i += NTH) {
    int row = i >> 7, k = i & 127;
    float v = x[(size_t)(b0 + row) * DIN + k];
    unsigned short h1 = f2bf(v);  float r1 = v - bf2f(h1);
    unsigned short h2 = f2bf(r1); float r2 = r1 - bf2f(h2);
    int kc = k >> 5, nt = row >> 4, lp = (row & 15) + 16 * ((k >> 3) & 3), j = k & 7;
    hp_s[HPS(0, kc, nt, lp, j)] = h1;
    hp_s[HPS(1, kc, nt, lp, j)] = h2;
    hp_s[HPS(2, kc, nt, lp, j)] = f2bf(r2);
  }
  // waves 2-3: generate step-0 gumbels while others head to barrier
  if (wave >= 2) gen_gumbel(gmb_s, 0, b0, wave - 2, lane, keys.a[0], keys.b[0]);
  __syncthreads();

  f32x4 acc0[4][2], acc1[4][2], z_s[4][2], hold[4][2];

  // ---- encoder: h0 = x @ W_enc + b_enc ----
#pragma unroll
  for (int mtl = 0; mtl < 4; ++mtl) {
    int mb = (wave * 4 + mtl) * 16 + qk * 4;
    f32x4 be = *(const f32x4*)&b_enc[mb];
#pragma unroll
    for (int nt = 0; nt < 2; ++nt) acc0[mtl][nt] = be;
  }
  gemm_pass<4, 1>(encf, nullptr, hp_s, wave, lane, acc0, acc1);
  __syncthreads();  // all x-plane reads done
#pragma unroll
  for (int mtl = 0; mtl < 4; ++mtl) {
    int mb = (wave * 4 + mtl) * 16 + qk * 4;
    int kc = mb >> 5, hi2 = (mb >> 3) & 3, j0 = mb & 7, lp = ln + 16 * hi2;
#pragma unroll
    for (int nt = 0; nt < 2; ++nt) {
      f32x4 o = acc0[mtl][nt];
      hold[mtl][nt] = o;                 // h_old lives in registers from here on
      bh4 P0, P1, P2;
#pragma unroll
      for (int j = 0; j < 4; ++j) {
        float v = o[j];
        unsigned short h1 = f2bf(v);  float r1 = v - bf2f(h1);
        unsigned short h2 = f2bf(r1); float r2 = r1 - bf2f(h2);
        P0[j] = (short)h1; P1[j] = (short)h2; P2[j] = (short)f2bf(r2);
      }
      *(bh4*)&hp_s[HPS(0, kc, nt, lp, j0)] = P0;
      *(bh4*)&hp_s[HPS(1, kc, nt, lp, j0)] = P1;
      *(bh4*)&hp_s[HPS(2, kc, nt, lp, j0)] = P2;
    }
  }
  __syncthreads();

#pragma unroll 1
  for (int t = 0; t < TS; ++t) {
    // ---- fused z+r (C-init from pre tables incl. bias) ----
#pragma unroll
    for (int mtl = 0; mtl < 4; ++mtl) {
      int mb = (wave * 4 + mtl) * 16 + qk * 4;
#pragma unroll
      for (int nt = 0; nt < 2; ++nt) {
        int code = (int)(state[nt * 16 + ln] & 7u);
        acc0[mtl][nt] = *(const f32x4*)&pre[(0 * 8 + code) * 256 + mb];
        acc1[mtl][nt] = *(const f32x4*)&pre[(1 * 8 + code) * 256 + mb];
      }
    }
    gemm_pass<8, 2>(zf, rf, hp_s, wave, lane, acc0, acc1);
    __syncthreads();  // all h-plane reads done
#pragma unroll
    for (int mtl = 0; mtl < 4; ++mtl) {
      int mb = (wave * 4 + mtl) * 16 + qk * 4;
      int kc = mb >> 5, hi2 = (mb >> 3) & 3, j0 = mb & 7, lp = ln + 16 * hi2;
#pragma unroll
      for (int nt = 0; nt < 2; ++nt) {
        f32x4 ho = hold[mtl][nt];
        f32x4 zv;
        bh4 P0, P1, P2;
#pragma unroll
        for (int j = 0; j < 4; ++j) {
          zv[j] = sigf(acc0[mtl][nt][j]);
          float rhv = sigf(acc1[mtl][nt][j]) * ho[j];
          unsigned short h1 = f2bf(rhv); float r1 = rhv - bf2f(h1);
          unsigned short h2 = f2bf(r1);  float r2 = r1 - bf2f(h2);
          P0[j] = (short)h1; P1[j] = (short)h2; P2[j] = (short)f2bf(r2);
        }
        z_s[mtl][nt] = zv;
        *(bh4*)&hp_s[HPS(0, kc, nt, lp, j0)] = P0;
        *(bh4*)&hp_s[HPS(1, kc, nt, lp, j0)] = P1;
        *(bh4*)&hp_s[HPS(2, kc, nt, lp, j0)] = P2;
      }
    }
    __syncthreads();  // rh planes published

    // ---- candidate gate ----
#pragma unroll
    for (int mtl = 0; mtl < 4; ++mtl) {
      int mb = (wave * 4 + mtl) * 16 + qk * 4;
#pragma unroll
      for (int nt = 0; nt < 2; ++nt) {
        int code = (int)(state[nt * 16 + ln] & 7u);
        acc0[mtl][nt] = *(const f32x4*)&pre[(2 * 8 + code) * 256 + mb];
      }
    }
    gemm_pass<8, 1>(hf, nullptr, hp_s, wave, lane, acc0, acc1);
    __syncthreads();  // all rh-plane reads done
#pragma unroll
    for (int mtl = 0; mtl < 4; ++mtl) {
      int mb = (wave * 4 + mtl) * 16 + qk * 4;
      int kc = mb >> 5, hi2 = (mb >> 3) & 3, j0 = mb & 7, lp = ln + 16 * hi2;
#pragma unroll
      for (int nt = 0; nt < 2; ++nt) {
        f32x4 z = z_s[mtl][nt], ho = hold[mtl][nt], hn;
        bh4 P0, P1, P2;
#pragma unroll
        for (int j = 0; j < 4; ++j) {
          float ht = tanhf(acc0[mtl][nt][j]);
          hn[j] = (1.0f - z[j]) * ho[j] + z[j] * ht;
          unsigned short h1 = f2bf(hn[j]); float r1 = hn[j] - bf2f(h1);
          unsigned short h2 = f2bf(r1);    float r2 = r1 - bf2f(h2);
          P0[j] = (short)h1; P1[j] = (short)h2; P2[j] = (short)f2bf(r2);
        }
        hold[mtl][nt] = hn;              // persists to next step
        *(bh4*)&hp_s[HPS(0, kc, nt, lp, j0)] = P0;
        *(bh4*)&hp_s[HPS(1, kc, nt, lp, j0)] = P1;
        *(bh4*)&hp_s[HPS(2, kc, nt, lp, j0)] = P2;
      }
    }
    __syncthreads();  // h_new planes visible

    // ---- logits GEMM (waves 0-1) || gumbel t+1 (waves 2-3) ----
    if (wave < 2) {
      f32x4 lacc;
#pragma unroll
      for (int j = 0; j < 4; ++j) lacc[j] = boutL[qk * 4 + j];
#pragma unroll 1
      for (int kc = 0; kc < 8; ++kc) {
        bfrag B0 = *(const bfrag*)&hp_s[HPS(0, kc, wave, lane, 0)];
        bfrag B1 = *(const bfrag*)&hp_s[HPS(1, kc, wave, lane, 0)];
        bfrag B2 = *(const bfrag*)&hp_s[HPS(2, kc, wave, lane, 0)];
        bfrag A[3];
#pragma unroll
        for (int p = 0; p < 3; ++p)
          A[p] = *(const bfrag*)(woutf + (p * 8 + kc) * 512 + lane * 8);
        lacc = prod6(A, B0, B1, B2, lacc);
      }
      // D[m=qk*4+j][n=ln]: vocab 0..3 at qk=0, vocab 4..5 at qk=1 regs 0..1
      float l4 = __shfl(lacc[0], ln + 16, 64);
      float l5 = __shfl(lacc[1], ln + 16, 64);
      if (qk == 0) {
        const int m = wave * 16 + ln;
        const int row = b0 + m;
        unsigned st = state[m];
        if (!(st & 8u)) {
          float l[VT] = {lacc[0], lacc[1], lacc[2], lacc[3], l4, l5};
          float best = 0.f; int tok = 0;
#pragma unroll
          for (int v = 0; v < VT; ++v) {
            float val = l[v] + gmb_s[((t & 1) * 32 + m) * 6 + v];
            if (v == 0 || val > best) { best = val; tok = v; }
          }
          float lmax = l[0];
#pragma unroll
          for (int v = 1; v < VT; ++v) lmax = fmaxf(lmax, l[v]);
          float s = 0.f;
#pragma unroll
          for (int v = 0; v < VT; ++v) s += expf(l[v] - lmax);
          float lp = (l[tok] - lmax) - logf(s);
          tlp[m] += lp;
          const bool is_stop = (tok == VT - 1);
          unsigned len = ((st >> 4) & 7u) + (is_stop ? 0u : 1u);
#pragma unroll
          for (int v = 0; v < VT; ++v)
            out[(size_t)row * (TS * VT) + t * VT + v] = (v == tok) ? 1.0f : 0.0f;
          state[m] = (unsigned)tok | (is_stop ? 8u : 0u) | (len << 4);
        } else {
#pragma unroll
          for (int v = 0; v < VT; ++v)
            out[(size_t)row * (TS * VT) + t * VT + v] = 0.0f;
          state[m] = 6u | 8u | (st & 0x70u);
        }
      }
    } else if (t + 1 < TS) {
      gen_gumbel(gmb_s, t + 1, b0, wave - 2, lane, keys.a[t + 1], keys.b[t + 1]);
    }
    __syncthreads();  // state/tlp/gumbels visible for next step
  }

  if (tid < BM) {
    const int row = b0 + tid;
    out[(size_t)NB * (TS * VT) + row]      = tlp[tid];
    out[(size_t)NB * (TS * VT) + NB + row] = (float)((state[tid] >> 4) & 7u);
  }
}

extern "C" void kernel_launch(void* const* d_in, const int* in_sizes, int n_in,
                              void* d_out, int out_size, void* d_ws, size_t ws_size,
                              hipStream_t stream) {
  (void)in_sizes; (void)n_in; (void)out_size; (void)ws_size;
  const float* x          = (const float*)d_in[0];
  const float* W_enc      = (const float*)d_in[1];
  const float* b_enc      = (const float*)d_in[2];
  const float* W_embed    = (const float*)d_in[3];
  const float* b_embed    = (const float*)d_in[4];
  const float* W_z        = (const float*)d_in[5];
  const float* b_z        = (const float*)d_in[6];
  const float* W_r        = (const float*)d_in[7];
  const float* b_r        = (const float*)d_in[8];
  const float* W_h        = (const float*)d_in[9];
  const float* b_h        = (const float*)d_in[10];
  const float* W_out      = (const float*)d_in[11];
  const float* b_out      = (const float*)d_in[12];
  const float* start_embed= (const float*)d_in[13];
  float* out = (float*)d_out;

  // workspace: pre [0,24576); enc frags [24576,221184); z [221184,614400);
  // r [614400,1007616); h [1007616,1400832); wout frags [1400832,1425408)
  float* pre = (float*)d_ws;
  unsigned short* encf = (unsigned short*)((char*)d_ws + 24576);
  unsigned short* zfb  = (unsigned short*)((char*)d_ws + 221184);
  unsigned short* rfb  = (unsigned short*)((char*)d_ws + 614400);
  unsigned short* hfb  = (unsigned short*)((char*)d_ws + 1007616);
  unsigned short* wof  = (unsigned short*)((char*)d_ws + 1400832);

  pre_kernel<<<138, 256, 0, stream>>>(W_enc, W_embed, b_embed, start_embed,
                                      W_z, b_z, W_r, b_r, W_h, b_h, W_out,
                                      pre, encf, zfb, rfb, hfb, wof);

  // keys = jax.random.split(jax.random.key(42), 6), partitionable mode
  Keys K;
  for (int t = 0; t < 6; ++t) {
    uint32_t o0, o1;
    tf2x32(0u, 42u, 0u, (uint32_t)t, o0, o1);
    K.a[t] = o0; K.b[t] = o1;
  }

  main_kernel<<<NB / BM, NTH, 0, stream>>>(x, b_enc, b_out,
                                           pre, encf, zfb, rfb, hfb, wof, out, K);
}

// Round 6
// 1968.373 us; speedup vs baseline: 1.1024x; 1.1024x over previous
//
#include <hip/hip_runtime.h>
#include <stdint.h>

// Problem constants
#define NB   131072
#define DIN  128
#define HD   256
#define VT   6
#define TS   6
// Tiling: BM=32 rows/block, 512 threads = 8 waves, each wave owns 32
// weight-cols (MT=2 MFMA tiles). Same block-level math as the 4-wave/64-col
// baseline, but per-wave register state halves (acc+acc1+hold = 48 f32 peak)
// -> target ~120 VGPR -> 4 waves/SIMD (2 blocks x 8 waves per CU) vs the
// baseline's 2 waves/SIMD at ~256 regs. TLP doubles to hide the L2 A-frag
// latency + barrier skew that hold the baseline at 44% MfmaUtil.
// MFMA 16x16x32 bf16; fp32 exact via 3-plane bf16 split (6 products).
#define BM   32
#define NTH  512
#define MT   2     // MFMA col-tiles per wave

typedef __attribute__((ext_vector_type(8))) short bfrag;   // 8 bf16 (4 VGPRs)
typedef __attribute__((ext_vector_type(4))) short bh4;     // 4 bf16
typedef __attribute__((ext_vector_type(4))) float f32x4;   // MFMA C/D

struct Keys { uint32_t a[6]; uint32_t b[6]; };

// hp plane layout: [p][kc][nt 2][lane 64][8] shorts, +16-short pad per (p,kc) block.
#define HPS(p, kc, nt, lp, j) ((((p) * 8 + (kc)) * 1040) + (nt) * 512 + (lp) * 8 + (j))

// ---- JAX threefry2x32 (20 rounds), bit-exact ----
__host__ __device__ inline void tf2x32(uint32_t k0, uint32_t k1,
                                       uint32_t c0, uint32_t c1,
                                       uint32_t& o0, uint32_t& o1) {
  uint32_t ks2 = k0 ^ k1 ^ 0x1BD11BDAu;
  uint32_t x0 = c0 + k0, x1 = c1 + k1;
#define TFR(d) { x0 += x1; x1 = (x1 << (d)) | (x1 >> (32 - (d))); x1 ^= x0; }
  TFR(13) TFR(15) TFR(26) TFR(6)
  x0 += k1;  x1 += ks2 + 1u;
  TFR(17) TFR(29) TFR(16) TFR(24)
  x0 += ks2; x1 += k0 + 2u;
  TFR(13) TFR(15) TFR(26) TFR(6)
  x0 += k0;  x1 += k1 + 3u;
  TFR(17) TFR(29) TFR(16) TFR(24)
  x0 += k1;  x1 += ks2 + 4u;
  TFR(13) TFR(15) TFR(26) TFR(6)
  x0 += ks2; x1 += k0 + 5u;
#undef TFR
  o0 = x0; o1 = x1;
}

__device__ __forceinline__ unsigned short f2bf(float x) {   // RNE f32->bf16
  uint32_t b = __float_as_uint(x);
  uint32_t r = b + 0x7FFFu + ((b >> 16) & 1u);
  return (unsigned short)(r >> 16);
}
__device__ __forceinline__ float bf2f(unsigned short u) {
  return __uint_as_float(((uint32_t)u) << 16);
}
__device__ __forceinline__ float sigf(float v) { return 1.0f / (1.0f + expf(-v)); }

#define MFMA16(a, b, c) __builtin_amdgcn_mfma_f32_16x16x32_bf16((a), (b), (c), 0, 0, 0)

// 6-product bf16x3: (hi,hi),(hi,mid),(mid,hi),(mid,mid),(hi,lo),(lo,hi)
__device__ __forceinline__ f32x4 prod6(const bfrag A[3], bfrag B0, bfrag B1, bfrag B2,
                                       f32x4 c) {
  c = MFMA16(A[0], B0, c);
  c = MFMA16(A[0], B1, c);
  c = MFMA16(A[1], B0, c);
  c = MFMA16(A[1], B1, c);
  c = MFMA16(A[0], B2, c);
  c = MFMA16(A[2], B0, c);
  return c;
}

// ---- Kernel A: pre tables (gate bias folded), W frags, W_out frags ----
// A-layout: ((p*KC + kc)*16 + mt)*512 + lane*8 + j holds
// A[m = mt*16 + (lane&15)][k = kc*32 + (lane>>4)*8 + j] = W[krow0+k][m].
__global__ void pre_kernel(const float* __restrict__ W_enc,
                           const float* __restrict__ W_embed,
                           const float* __restrict__ b_embed,
                           const float* __restrict__ start_embed,
                           const float* __restrict__ W_z, const float* __restrict__ b_z,
                           const float* __restrict__ W_r, const float* __restrict__ b_r,
                           const float* __restrict__ W_h, const float* __restrict__ b_h,
                           const float* __restrict__ W_out,
                           float* __restrict__ pre,
                           unsigned short* __restrict__ encf,
                           unsigned short* __restrict__ zf,
                           unsigned short* __restrict__ rf,
                           unsigned short* __restrict__ hf,
                           unsigned short* __restrict__ woutf) {
  const int bid = blockIdx.x;
  if (bid < 24) {  // pre tables: codes 0..5 = W_embed[c]+b_embed, 6 = b_embed, 7 = start
    __shared__ float xin[HD];
    const int c = bid & 7, g = bid >> 3, j = threadIdx.x;
    float v;
    if (c < 6)       v = W_embed[c * HD + j] + b_embed[j];
    else if (c == 6) v = b_embed[j];
    else             v = start_embed[j];
    xin[j] = v;
    __syncthreads();
    const float* Wg = (g == 0) ? W_z : (g == 1) ? W_r : W_h;  // top half rows 0..255
    const float* bg = (g == 0) ? b_z : (g == 1) ? b_r : b_h;
    float acc = bg[j];                       // fold gate bias into pre table
    for (int k = 0; k < HD; ++k) acc += xin[k] * Wg[k * HD + j];
    pre[(g * 8 + c) * HD + j] = acc;
    return;
  }
  if (bid >= 136) {  // W_out frags: single mt, KC=8; A[m][k] = W_out[k][m] (m<6)
    int id2 = (bid - 136) * 256 + threadIdx.x;   // 0..511
    int kc = id2 >> 6, lane = id2 & 63;
    int m = lane & 15, k0 = kc * 32 + ((lane >> 4) & 3) * 8;
    __align__(16) unsigned short P[3][8];
#pragma unroll
    for (int j = 0; j < 8; ++j) {
      float w = (m < VT) ? W_out[(size_t)(k0 + j) * VT + m] : 0.f;
      unsigned short h1 = f2bf(w);  float r1 = w - bf2f(h1);
      unsigned short h2 = f2bf(r1); float r2 = r1 - bf2f(h2);
      P[0][j] = h1; P[1][j] = h2; P[2][j] = f2bf(r2);
    }
    for (int p = 0; p < 3; ++p) {
      unsigned short* d = woutf + ((size_t)(p * 8 + kc) * 512) + (size_t)lane * 8;
      *(uint4*)d = *(const uint4*)P[p];
    }
    return;
  }
  int id = (bid - 24) * 256 + threadIdx.x;   // 0 .. 28671
  const float* src; unsigned short* dst; int kc, mt, lane, KC, krow0;
  if (id < 4096) {            // encoder frags: KC=4 (K=128)
    lane = id & 63; mt = (id >> 6) & 15; kc = id >> 10;
    src = W_enc; dst = encf; KC = 4; krow0 = 0;
  } else {                    // gate frags: KC=8 (K=256), bottom half rows 256..511
    int rem = id - 4096; int g = rem >> 13; int rr = rem & 8191;
    lane = rr & 63; mt = (rr >> 6) & 15; kc = rr >> 10;
    src = (g == 0) ? W_z : (g == 1) ? W_r : W_h;
    dst = (g == 0) ? zf  : (g == 1) ? rf  : hf;
    KC = 8; krow0 = 256;
  }
  const int m  = mt * 16 + (lane & 15);
  const int k0 = kc * 32 + ((lane >> 4) & 3) * 8;
  __align__(16) unsigned short P[3][8];
#pragma unroll
  for (int j = 0; j < 8; ++j) {
    float w = src[(size_t)(krow0 + k0 + j) * HD + m];
    unsigned short h1 = f2bf(w);  float r1 = w - bf2f(h1);
    unsigned short h2 = f2bf(r1); float r2 = r1 - bf2f(h2);
    P[0][j] = h1; P[1][j] = h2; P[2][j] = f2bf(r2);   // hi+mid+lo == w exactly
  }
  for (int p = 0; p < 3; ++p) {
    unsigned short* d = dst + ((size_t)(p * KC + kc) * 16 + mt) * 512 + (size_t)lane * 8;
    *(uint4*)d = *(const uint4*)P[p];
  }
}

// GEMM pass: A = W frags (global/L2), B = h planes (LDS, conflict-free).
// Wave owns mt = wave*MT + mtl (MT=2). NG=2 shares B across two A streams
// (z+r fused). Serial structure (the proven-clean baseline schedule).
template<int KC, int NG>
__device__ __forceinline__ void gemm_pass(const unsigned short* __restrict__ f0,
                                          const unsigned short* __restrict__ f1,
                                          const unsigned short* hp_s,
                                          int wave, int lane,
                                          f32x4 acc0[MT][2], f32x4 acc1[MT][2]) {
#pragma unroll 1
  for (int kc = 0; kc < KC; ++kc) {
    bfrag B[3][2];
#pragma unroll
    for (int p = 0; p < 3; ++p)
#pragma unroll
      for (int nt = 0; nt < 2; ++nt)
        B[p][nt] = *(const bfrag*)&hp_s[HPS(p, kc, nt, lane, 0)];
#pragma unroll
    for (int mtl = 0; mtl < MT; ++mtl) {
      const int fo = (kc * 16 + wave * MT + mtl) * 512 + lane * 8;
      bfrag A0[3], A1[3];
#pragma unroll
      for (int p = 0; p < 3; ++p) A0[p] = *(const bfrag*)(f0 + fo + p * (KC * 8192));
      if (NG == 2) {
#pragma unroll
        for (int p = 0; p < 3; ++p) A1[p] = *(const bfrag*)(f1 + fo + p * (KC * 8192));
      }
#pragma unroll
      for (int nt = 0; nt < 2; ++nt) {
        acc0[mtl][nt] = prod6(A0, B[0][nt], B[1][nt], B[2][nt], acc0[mtl][nt]);
        if (NG == 2)
          acc1[mtl][nt] = prod6(A1, B[0][nt], B[1][nt], B[2][nt], acc1[mtl][nt]);
      }
    }
  }
}

// gumbel batch for step s, tile (16 rows), into double-buffered LDS
__device__ __forceinline__ void gen_gumbel(float* __restrict__ gmb, int s, int b0,
                                           int tile, int lane,
                                           uint32_t ka, uint32_t kb) {
  uint32_t basej = (uint32_t)(b0 + tile * 16) * 6u;
#pragma unroll
  for (int rep = 0; rep < 2; ++rep) {
    int d = rep * 64 + lane;
    if (d < 96) {
      uint32_t o0, o1;
      tf2x32(ka, kb, 0u, basej + (uint32_t)d, o0, o1);
      uint32_t bits = o0 ^ o1;
      float f = __uint_as_float((bits >> 9) | 0x3f800000u) - 1.0f;
      float u = (f > 0.f) ? f : 1.175494350822288e-38f;
      float lg1 = (float)log((double)u);
      float lg2 = (float)log((double)(-lg1));
      gmb[((s & 1) * 32 + tile * 16 + d / 6) * 6 + (d % 6)] = -lg2;
    }
  }
}

// ---- main kernel: persistent rollout; h_old in registers; logits via MFMA;
// gumbels generated by waves 2-3 overlapped with waves 0-1's logits GEMM;
// waves 4-7 carry only GEMM/pack work (idle in the sample phase).
__launch_bounds__(NTH, 4)
__global__ void main_kernel(const float* __restrict__ x,
                            const float* __restrict__ b_enc,
                            const float* __restrict__ b_out,
                            const float* __restrict__ pre,
                            const unsigned short* __restrict__ encf,
                            const unsigned short* __restrict__ zf,
                            const unsigned short* __restrict__ rf,
                            const unsigned short* __restrict__ hf,
                            const unsigned short* __restrict__ woutf,
                            float* __restrict__ out, Keys keys) {
  __shared__ __align__(16) unsigned short hp_s[3 * 8 * 1040];  // 49,920 B
  __shared__ float gmb_s[2 * 32 * 6];                          //  1,536 B
  __shared__ float boutL[16];
  __shared__ unsigned state[BM];
  __shared__ float tlp[BM];
  // total ~51.8 KB -> 2 blocks/CU; 16 waves/CU if VGPR <= 128

  const int tid = threadIdx.x;
  const int wave = tid >> 6, lane = tid & 63;
  const int ln = lane & 15, qk = lane >> 4;
  const int b0 = blockIdx.x * BM;

  if (tid < 16) boutL[tid] = (tid < VT) ? b_out[tid] : 0.f;
  if (tid < BM) { state[tid] = 7u; tlp[tid] = 0.f; }

  // stage x (B-operand planes), kc 0..3
  for (int i = tid; i < BM * DIN; i += NTH) {
    int row = i >> 7, k = i & 127;
    float v = x[(size_t)(b0 + row) * DIN + k];
    unsigned short h1 = f2bf(v);  float r1 = v - bf2f(h1);
    unsigned short h2 = f2bf(r1); float r2 = r1 - bf2f(h2);
    int kc = k >> 5, nt = row >> 4, lp = (row & 15) + 16 * ((k >> 3) & 3), j = k & 7;
    hp_s[HPS(0, kc, nt, lp, j)] = h1;
    hp_s[HPS(1, kc, nt, lp, j)] = h2;
    hp_s[HPS(2, kc, nt, lp, j)] = f2bf(r2);
  }
  // waves 2-3: generate step-0 gumbels while others head to barrier
  if (wave == 2 || wave == 3)
    gen_gumbel(gmb_s, 0, b0, wave - 2, lane, keys.a[0], keys.b[0]);
  __syncthreads();

  f32x4 acc0[MT][2], acc1[MT][2], z_s[MT][2], hold[MT][2];

  // ---- encoder: h0 = x @ W_enc + b_enc ----
#pragma unroll
  for (int mtl = 0; mtl < MT; ++mtl) {
    int mb = (wave * MT + mtl) * 16 + qk * 4;
    f32x4 be = *(const f32x4*)&b_enc[mb];
#pragma unroll
    for (int nt = 0; nt < 2; ++nt) acc0[mtl][nt] = be;
  }
  gemm_pass<4, 1>(encf, nullptr, hp_s, wave, lane, acc0, acc1);
  __syncthreads();  // all x-plane reads done
#pragma unroll
  for (int mtl = 0; mtl < MT; ++mtl) {
    int mb = (wave * MT + mtl) * 16 + qk * 4;
    int kc = mb >> 5, hi2 = (mb >> 3) & 3, j0 = mb & 7, lp = ln + 16 * hi2;
#pragma unroll
    for (int nt = 0; nt < 2; ++nt) {
      f32x4 o = acc0[mtl][nt];
      hold[mtl][nt] = o;                 // h_old lives in registers from here on
      bh4 P0, P1, P2;
#pragma unroll
      for (int j = 0; j < 4; ++j) {
        float v = o[j];
        unsigned short h1 = f2bf(v);  float r1 = v - bf2f(h1);
        unsigned short h2 = f2bf(r1); float r2 = r1 - bf2f(h2);
        P0[j] = (short)h1; P1[j] = (short)h2; P2[j] = (short)f2bf(r2);
      }
      *(bh4*)&hp_s[HPS(0, kc, nt, lp, j0)] = P0;
      *(bh4*)&hp_s[HPS(1, kc, nt, lp, j0)] = P1;
      *(bh4*)&hp_s[HPS(2, kc, nt, lp, j0)] = P2;
    }
  }
  __syncthreads();

#pragma unroll 1
  for (int t = 0; t < TS; ++t) {
    // ---- fused z+r (C-init from pre tables incl. bias) ----
#pragma unroll
    for (int mtl = 0; mtl < MT; ++mtl) {
      int mb = (wave * MT + mtl) * 16 + qk * 4;
#pragma unroll
      for (int nt = 0; nt < 2; ++nt) {
        int code = (int)(state[nt * 16 + ln] & 7u);
        acc0[mtl][nt] = *(const f32x4*)&pre[(0 * 8 + code) * 256 + mb];
        acc1[mtl][nt] = *(const f32x4*)&pre[(1 * 8 + code) * 256 + mb];
      }
    }
    gemm_pass<8, 2>(zf, rf, hp_s, wave, lane, acc0, acc1);
    __syncthreads();  // all h-plane reads done
#pragma unroll
    for (int mtl = 0; mtl < MT; ++mtl) {
      int mb = (wave * MT + mtl) * 16 + qk * 4;
      int kc = mb >> 5, hi2 = (mb >> 3) & 3, j0 = mb & 7, lp = ln + 16 * hi2;
#pragma unroll
      for (int nt = 0; nt < 2; ++nt) {
        f32x4 ho = hold[mtl][nt];
        f32x4 zv;
        bh4 P0, P1, P2;
#pragma unroll
        for (int j = 0; j < 4; ++j) {
          zv[j] = sigf(acc0[mtl][nt][j]);
          float rhv = sigf(acc1[mtl][nt][j]) * ho[j];
          unsigned short h1 = f2bf(rhv); float r1 = rhv - bf2f(h1);
          unsigned short h2 = f2bf(r1);  float r2 = r1 - bf2f(h2);
          P0[j] = (short)h1; P1[j] = (short)h2; P2[j] = (short)f2bf(r2);
        }
        z_s[mtl][nt] = zv;
        *(bh4*)&hp_s[HPS(0, kc, nt, lp, j0)] = P0;
        *(bh4*)&hp_s[HPS(1, kc, nt, lp, j0)] = P1;
        *(bh4*)&hp_s[HPS(2, kc, nt, lp, j0)] = P2;
      }
    }
    __syncthreads();  // rh planes published

    // ---- candidate gate ----
#pragma unroll
    for (int mtl = 0; mtl < MT; ++mtl) {
      int mb = (wave * MT + mtl) * 16 + qk * 4;
#pragma unroll
      for (int nt = 0; nt < 2; ++nt) {
        int code = (int)(state[nt * 16 + ln] & 7u);
        acc0[mtl][nt] = *(const f32x4*)&pre[(2 * 8 + code) * 256 + mb];
      }
    }
    gemm_pass<8, 1>(hf, nullptr, hp_s, wave, lane, acc0, acc1);
    __syncthreads();  // all rh-plane reads done
#pragma unroll
    for (int mtl = 0; mtl < MT; ++mtl) {
      int mb = (wave * MT + mtl) * 16 + qk * 4;
      int kc = mb >> 5, hi2 = (mb >> 3) & 3, j0 = mb & 7, lp = ln + 16 * hi2;
#pragma unroll
      for (int nt = 0; nt < 2; ++nt) {
        f32x4 z = z_s[mtl][nt], ho = hold[mtl][nt], hn;
        bh4 P0, P1, P2;
#pragma unroll
        for (int j = 0; j < 4; ++j) {
          float ht = tanhf(acc0[mtl][nt][j]);
          hn[j] = (1.0f - z[j]) * ho[j] + z[j] * ht;
          unsigned short h1 = f2bf(hn[j]); float r1 = hn[j] - bf2f(h1);
          unsigned short h2 = f2bf(r1);    float r2 = r1 - bf2f(h2);
          P0[j] = (short)h1; P1[j] = (short)h2; P2[j] = (short)f2bf(r2);
        }
        hold[mtl][nt] = hn;              // persists to next step
        *(bh4*)&hp_s[HPS(0, kc, nt, lp, j0)] = P0;
        *(bh4*)&hp_s[HPS(1, kc, nt, lp, j0)] = P1;
        *(bh4*)&hp_s[HPS(2, kc, nt, lp, j0)] = P2;
      }
    }
    __syncthreads();  // h_new planes visible

    // ---- logits GEMM (waves 0-1) || gumbel t+1 (waves 2-3) ----
    if (wave < 2) {
      f32x4 lacc;
#pragma unroll
      for (int j = 0; j < 4; ++j) lacc[j] = boutL[qk * 4 + j];
#pragma unroll 1
      for (int kc = 0; kc < 8; ++kc) {
        bfrag B0 = *(const bfrag*)&hp_s[HPS(0, kc, wave, lane, 0)];
        bfrag B1 = *(const bfrag*)&hp_s[HPS(1, kc, wave, lane, 0)];
        bfrag B2 = *(const bfrag*)&hp_s[HPS(2, kc, wave, lane, 0)];
        bfrag A[3];
#pragma unroll
        for (int p = 0; p < 3; ++p)
          A[p] = *(const bfrag*)(woutf + (p * 8 + kc) * 512 + lane * 8);
        lacc = prod6(A, B0, B1, B2, lacc);
      }
      // D[m=qk*4+j][n=ln]: vocab 0..3 at qk=0, vocab 4..5 at qk=1 regs 0..1
      float l4 = __shfl(lacc[0], ln + 16, 64);
      float l5 = __shfl(lacc[1], ln + 16, 64);
      if (qk == 0) {
        const int m = wave * 16 + ln;
        const int row = b0 + m;
        unsigned st = state[m];
        if (!(st & 8u)) {
          float l[VT] = {lacc[0], lacc[1], lacc[2], lacc[3], l4, l5};
          float best = 0.f; int tok = 0;
#pragma unroll
          for (int v = 0; v < VT; ++v) {
            float val = l[v] + gmb_s[((t & 1) * 32 + m) * 6 + v];
            if (v == 0 || val > best) { best = val; tok = v; }
          }
          float lmax = l[0];
#pragma unroll
          for (int v = 1; v < VT; ++v) lmax = fmaxf(lmax, l[v]);
          float s = 0.f;
#pragma unroll
          for (int v = 0; v < VT; ++v) s += expf(l[v] - lmax);
          float lp = (l[tok] - lmax) - logf(s);
          tlp[m] += lp;
          const bool is_stop = (tok == VT - 1);
          unsigned len = ((st >> 4) & 7u) + (is_stop ? 0u : 1u);
#pragma unroll
          for (int v = 0; v < VT; ++v)
            out[(size_t)row * (TS * VT) + t * VT + v] = (v == tok) ? 1.0f : 0.0f;
          state[m] = (unsigned)tok | (is_stop ? 8u : 0u) | (len << 4);
        } else {
#pragma unroll
          for (int v = 0; v < VT; ++v)
            out[(size_t)row * (TS * VT) + t * VT + v] = 0.0f;
          state[m] = 6u | 8u | (st & 0x70u);
        }
      }
    } else if ((wave == 2 || wave == 3) && t + 1 < TS) {
      gen_gumbel(gmb_s, t + 1, b0, wave - 2, lane, keys.a[t + 1], keys.b[t + 1]);
    }
    __syncthreads();  // state/tlp/gumbels visible for next step
  }

  if (tid < BM) {
    const int row = b0 + tid;
    out[(size_t)NB * (TS * VT) + row]      = tlp[tid];
    out[(size_t)NB * (TS * VT) + NB + row] = (float)((state[tid] >> 4) & 7u);
  }
}

extern "C" void kernel_launch(void* const* d_in, const int* in_sizes, int n_in,
                              void* d_out, int out_size, void* d_ws, size_t ws_size,
                              hipStream_t stream) {
  (void)in_sizes; (void)n_in; (void)out_size; (void)ws_size;
  const float* x          = (const float*)d_in[0];
  const float* W_enc      = (const float*)d_in[1];
  const float* b_enc      = (const float*)d_in[2];
  const float* W_embed    = (const float*)d_in[3];
  const float* b_embed    = (const float*)d_in[4];
  const float* W_z        = (const float*)d_in[5];
  const float* b_z        = (const float*)d_in[6];
  const float* W_r        = (const float*)d_in[7];
  const float* b_r        = (const float*)d_in[8];
  const float* W_h        = (const float*)d_in[9];
  const float* b_h        = (const float*)d_in[10];
  const float* W_out      = (const float*)d_in[11];
  const float* b_out      = (const float*)d_in[12];
  const float* start_embed= (const float*)d_in[13];
  float* out = (float*)d_out;

  // workspace: pre [0,24576); enc frags [24576,221184); z [221184,614400);
  // r [614400,1007616); h [1007616,1400832); wout frags [1400832,1425408)
  float* pre = (float*)d_ws;
  unsigned short* encf = (unsigned short*)((char*)d_ws + 24576);
  unsigned short* zfb  = (unsigned short*)((char*)d_ws + 221184);
  unsigned short* rfb  = (unsigned short*)((char*)d_ws + 614400);
  unsigned short* hfb  = (unsigned short*)((char*)d_ws + 1007616);
  unsigned short* wof  = (unsigned short*)((char*)d_ws + 1400832);

  pre_kernel<<<138, 256, 0, stream>>>(W_enc, W_embed, b_embed, start_embed,
                                      W_z, b_z, W_r, b_r, W_h, b_h, W_out,
                                      pre, encf, zfb, rfb, hfb, wof);

  // keys = jax.random.split(jax.random.key(42), 6), partitionable mode
  Keys K;
  for (int t = 0; t < 6; ++t) {
    uint32_t o0, o1;
    tf2x32(0u, 42u, 0u, (uint32_t)t, o0, o1);
    K.a[t] = o0; K.b[t] = o1;
  }

  main_kernel<<<NB / BM, NTH, 0, stream>>>(x, b_enc, b_out,
                                           pre, encf, zfb, rfb, hfb, wof, out, K);
}

// Round 7
// 1870.421 us; speedup vs baseline: 1.1602x; 1.0524x over previous
//
#include <hip/hip_runtime.h>
#include <stdint.h>

// Problem constants
#define NB   131072
#define DIN  128
#define HD   256
#define VT   6
#define TS   6
// Tiling: BM=64 rows/block, 512 threads = 8 waves, each wave owns 32
// weight-cols (MT=2) x all 4 row-tiles (nt=0..3). ONE block/CU (LDS ~103KB).
// Rationale (R0-R6 counters): with BM=32 x 2 blocks/CU, the W-fragment
// stream from L2 is read twice per CU per step -> 53 B/cyc/CU demand during
// GEMM phases vs ~56 B/cyc per-CU L2 slice: L2-BW-bound at 44-49% MfmaUtil.
// BM=64 x 1 block halves A-traffic per row (26 B/cyc) and doubles per-wave
// MFMA per load batch. Register state (acc0/acc1/z_s/hold = 128 f32) equals
// the proven spill-free baseline; launch_bounds(512,2) leaves 256 regs/wave.
// MFMA 16x16x32 bf16; fp32 exact via 3-plane bf16 split (6 products).
#define BM   64
#define NTH  512
#define MT   2     // MFMA col-tiles per wave (8 waves x 2 = 16 tiles = 256 cols)

typedef __attribute__((ext_vector_type(8))) short bfrag;   // 8 bf16 (4 VGPRs)
typedef __attribute__((ext_vector_type(4))) short bh4;     // 4 bf16
typedef __attribute__((ext_vector_type(4))) float f32x4;   // MFMA C/D

struct Keys { uint32_t a[6]; uint32_t b[6]; };

// hp plane layout: [p][kc][nt 4][lane 64][8] shorts, +16-short pad per (p,kc)
// block (2064 = 4*512+16; preserves the 8-bank stagger of the 1040 layout).
#define HPS(p, kc, nt, lp, j) ((((p) * 8 + (kc)) * 2064) + (nt) * 512 + (lp) * 8 + (j))

// ---- JAX threefry2x32 (20 rounds), bit-exact ----
__host__ __device__ inline void tf2x32(uint32_t k0, uint32_t k1,
                                       uint32_t c0, uint32_t c1,
                                       uint32_t& o0, uint32_t& o1) {
  uint32_t ks2 = k0 ^ k1 ^ 0x1BD11BDAu;
  uint32_t x0 = c0 + k0, x1 = c1 + k1;
#define TFR(d) { x0 += x1; x1 = (x1 << (d)) | (x1 >> (32 - (d))); x1 ^= x0; }
  TFR(13) TFR(15) TFR(26) TFR(6)
  x0 += k1;  x1 += ks2 + 1u;
  TFR(17) TFR(29) TFR(16) TFR(24)
  x0 += ks2; x1 += k0 + 2u;
  TFR(13) TFR(15) TFR(26) TFR(6)
  x0 += k0;  x1 += k1 + 3u;
  TFR(17) TFR(29) TFR(16) TFR(24)
  x0 += k1;  x1 += ks2 + 4u;
  TFR(13) TFR(15) TFR(26) TFR(6)
  x0 += ks2; x1 += k0 + 5u;
#undef TFR
  o0 = x0; o1 = x1;
}

__device__ __forceinline__ unsigned short f2bf(float x) {   // RNE f32->bf16
  uint32_t b = __float_as_uint(x);
  uint32_t r = b + 0x7FFFu + ((b >> 16) & 1u);
  return (unsigned short)(r >> 16);
}
__device__ __forceinline__ float bf2f(unsigned short u) {
  return __uint_as_float(((uint32_t)u) << 16);
}
__device__ __forceinline__ float sigf(float v) { return 1.0f / (1.0f + expf(-v)); }

#define MFMA16(a, b, c) __builtin_amdgcn_mfma_f32_16x16x32_bf16((a), (b), (c), 0, 0, 0)

// 6-product bf16x3: (hi,hi),(hi,mid),(mid,hi),(mid,mid),(hi,lo),(lo,hi)
__device__ __forceinline__ f32x4 prod6(const bfrag A[3], bfrag B0, bfrag B1, bfrag B2,
                                       f32x4 c) {
  c = MFMA16(A[0], B0, c);
  c = MFMA16(A[0], B1, c);
  c = MFMA16(A[1], B0, c);
  c = MFMA16(A[1], B1, c);
  c = MFMA16(A[0], B2, c);
  c = MFMA16(A[2], B0, c);
  return c;
}

// ---- Kernel A: pre tables (gate bias folded), W frags, W_out frags ----
// A-layout: ((p*KC + kc)*16 + mt)*512 + lane*8 + j holds
// A[m = mt*16 + (lane&15)][k = kc*32 + (lane>>4)*8 + j] = W[krow0+k][m].
__global__ void pre_kernel(const float* __restrict__ W_enc,
                           const float* __restrict__ W_embed,
                           const float* __restrict__ b_embed,
                           const float* __restrict__ start_embed,
                           const float* __restrict__ W_z, const float* __restrict__ b_z,
                           const float* __restrict__ W_r, const float* __restrict__ b_r,
                           const float* __restrict__ W_h, const float* __restrict__ b_h,
                           const float* __restrict__ W_out,
                           float* __restrict__ pre,
                           unsigned short* __restrict__ encf,
                           unsigned short* __restrict__ zf,
                           unsigned short* __restrict__ rf,
                           unsigned short* __restrict__ hf,
                           unsigned short* __restrict__ woutf) {
  const int bid = blockIdx.x;
  if (bid < 24) {  // pre tables: codes 0..5 = W_embed[c]+b_embed, 6 = b_embed, 7 = start
    __shared__ float xin[HD];
    const int c = bid & 7, g = bid >> 3, j = threadIdx.x;
    float v;
    if (c < 6)       v = W_embed[c * HD + j] + b_embed[j];
    else if (c == 6) v = b_embed[j];
    else             v = start_embed[j];
    xin[j] = v;
    __syncthreads();
    const float* Wg = (g == 0) ? W_z : (g == 1) ? W_r : W_h;  // top half rows 0..255
    const float* bg = (g == 0) ? b_z : (g == 1) ? b_r : b_h;
    float acc = bg[j];                       // fold gate bias into pre table
    for (int k = 0; k < HD; ++k) acc += xin[k] * Wg[k * HD + j];
    pre[(g * 8 + c) * HD + j] = acc;
    return;
  }
  if (bid >= 136) {  // W_out frags: single mt, KC=8; A[m][k] = W_out[k][m] (m<6)
    int id2 = (bid - 136) * 256 + threadIdx.x;   // 0..511
    int kc = id2 >> 6, lane = id2 & 63;
    int m = lane & 15, k0 = kc * 32 + ((lane >> 4) & 3) * 8;
    __align__(16) unsigned short P[3][8];
#pragma unroll
    for (int j = 0; j < 8; ++j) {
      float w = (m < VT) ? W_out[(size_t)(k0 + j) * VT + m] : 0.f;
      unsigned short h1 = f2bf(w);  float r1 = w - bf2f(h1);
      unsigned short h2 = f2bf(r1); float r2 = r1 - bf2f(h2);
      P[0][j] = h1; P[1][j] = h2; P[2][j] = f2bf(r2);
    }
    for (int p = 0; p < 3; ++p) {
      unsigned short* d = woutf + ((size_t)(p * 8 + kc) * 512) + (size_t)lane * 8;
      *(uint4*)d = *(const uint4*)P[p];
    }
    return;
  }
  int id = (bid - 24) * 256 + threadIdx.x;   // 0 .. 28671
  const float* src; unsigned short* dst; int kc, mt, lane, KC, krow0;
  if (id < 4096) {            // encoder frags: KC=4 (K=128)
    lane = id & 63; mt = (id >> 6) & 15; kc = id >> 10;
    src = W_enc; dst = encf; KC = 4; krow0 = 0;
  } else {                    // gate frags: KC=8 (K=256), bottom half rows 256..511
    int rem = id - 4096; int g = rem >> 13; int rr = rem & 8191;
    lane = rr & 63; mt = (rr >> 6) & 15; kc = rr >> 10;
    src = (g == 0) ? W_z : (g == 1) ? W_r : W_h;
    dst = (g == 0) ? zf  : (g == 1) ? rf  : hf;
    KC = 8; krow0 = 256;
  }
  const int m  = mt * 16 + (lane & 15);
  const int k0 = kc * 32 + ((lane >> 4) & 3) * 8;
  __align__(16) unsigned short P[3][8];
#pragma unroll
  for (int j = 0; j < 8; ++j) {
    float w = src[(size_t)(krow0 + k0 + j) * HD + m];
    unsigned short h1 = f2bf(w);  float r1 = w - bf2f(h1);
    unsigned short h2 = f2bf(r1); float r2 = r1 - bf2f(h2);
    P[0][j] = h1; P[1][j] = h2; P[2][j] = f2bf(r2);   // hi+mid+lo == w exactly
  }
  for (int p = 0; p < 3; ++p) {
    unsigned short* d = dst + ((size_t)(p * KC + kc) * 16 + mt) * 512 + (size_t)lane * 8;
    *(uint4*)d = *(const uint4*)P[p];
  }
}

// GEMM pass: A = W frags (global/L2), B = h planes (LDS, conflict-free).
// Wave owns mt = wave*MT + mtl, all 4 nt row-tiles. NG=2 shares A/B across
// two accumulator streams (z+r fused). A loaded once per (kc,mtl); B once
// per (kc,nt): minimal L2 traffic. Serial (proven-clean) schedule.
template<int KC, int NG>
__device__ __forceinline__ void gemm_pass(const unsigned short* __restrict__ f0,
                                          const unsigned short* __restrict__ f1,
                                          const unsigned short* hp_s,
                                          int wave, int lane,
                                          f32x4 acc0[MT][4], f32x4 acc1[MT][4]) {
#pragma unroll 1
  for (int kc = 0; kc < KC; ++kc) {
    bfrag B[3][4];
#pragma unroll
    for (int p = 0; p < 3; ++p)
#pragma unroll
      for (int nt = 0; nt < 4; ++nt)
        B[p][nt] = *(const bfrag*)&hp_s[HPS(p, kc, nt, lane, 0)];
#pragma unroll
    for (int mtl = 0; mtl < MT; ++mtl) {
      const int fo = (kc * 16 + wave * MT + mtl) * 512 + lane * 8;
      bfrag A0[3], A1[3];
#pragma unroll
      for (int p = 0; p < 3; ++p) A0[p] = *(const bfrag*)(f0 + fo + p * (KC * 8192));
      if (NG == 2) {
#pragma unroll
        for (int p = 0; p < 3; ++p) A1[p] = *(const bfrag*)(f1 + fo + p * (KC * 8192));
      }
#pragma unroll
      for (int nt = 0; nt < 4; ++nt) {
        acc0[mtl][nt] = prod6(A0, B[0][nt], B[1][nt], B[2][nt], acc0[mtl][nt]);
        if (NG == 2)
          acc1[mtl][nt] = prod6(A1, B[0][nt], B[1][nt], B[2][nt], acc1[mtl][nt]);
      }
    }
  }
}

// gumbel batch for step s, tile (16 rows), into double-buffered LDS
__device__ __forceinline__ void gen_gumbel(float* __restrict__ gmb, int s, int b0,
                                           int tile, int lane,
                                           uint32_t ka, uint32_t kb) {
  uint32_t basej = (uint32_t)(b0 + tile * 16) * 6u;
#pragma unroll
  for (int rep = 0; rep < 2; ++rep) {
    int d = rep * 64 + lane;
    if (d < 96) {
      uint32_t o0, o1;
      tf2x32(ka, kb, 0u, basej + (uint32_t)d, o0, o1);
      uint32_t bits = o0 ^ o1;
      float f = __uint_as_float((bits >> 9) | 0x3f800000u) - 1.0f;
      float u = (f > 0.f) ? f : 1.175494350822288e-38f;
      float lg1 = (float)log((double)u);
      float lg2 = (float)log((double)(-lg1));
      gmb[((s & 1) * BM + tile * 16 + d / 6) * 6 + (d % 6)] = -lg2;
    }
  }
}

// ---- main kernel: persistent rollout; h_old in registers; logits via MFMA;
// waves 0-3 sample (one nt row-tile each), waves 4-7 generate next gumbels.
__launch_bounds__(NTH, 2)
__global__ void main_kernel(const float* __restrict__ x,
                            const float* __restrict__ b_enc,
                            const float* __restrict__ b_out,
                            const float* __restrict__ pre,
                            const unsigned short* __restrict__ encf,
                            const unsigned short* __restrict__ zf,
                            const unsigned short* __restrict__ rf,
                            const unsigned short* __restrict__ hf,
                            const unsigned short* __restrict__ woutf,
                            float* __restrict__ out, Keys keys) {
  __shared__ __align__(16) unsigned short hp_s[3 * 8 * 2064];  // 99,072 B
  __shared__ float gmb_s[2 * BM * 6];                          //  3,072 B
  __shared__ float boutL[16];
  __shared__ unsigned state[BM];
  __shared__ float tlp[BM];
  // total ~102.8 KB -> 1 block/CU, 8 waves (2 waves/SIMD)

  const int tid = threadIdx.x;
  const int wave = tid >> 6, lane = tid & 63;
  const int ln = lane & 15, qk = lane >> 4;
  const int b0 = blockIdx.x * BM;

  if (tid < 16) boutL[tid] = (tid < VT) ? b_out[tid] : 0.f;
  if (tid < BM) { state[tid] = 7u; tlp[tid] = 0.f; }

  // stage x (B-operand planes), kc 0..3, rows 0..63
  for (int i = tid; i < BM * DIN; i += NTH) {
    int row = i >> 7, k = i & 127;
    float v = x[(size_t)(b0 + row) * DIN + k];
    unsigned short h1 = f2bf(v);  float r1 = v - bf2f(h1);
    unsigned short h2 = f2bf(r1); float r2 = r1 - bf2f(h2);
    int kc = k >> 5, nt = row >> 4, lp = (row & 15) + 16 * ((k >> 3) & 3), j = k & 7;
    hp_s[HPS(0, kc, nt, lp, j)] = h1;
    hp_s[HPS(1, kc, nt, lp, j)] = h2;
    hp_s[HPS(2, kc, nt, lp, j)] = f2bf(r2);
  }
  // waves 4-7: generate step-0 gumbels (tiles 0-3) while others hit barrier
  if (wave >= 4) gen_gumbel(gmb_s, 0, b0, wave - 4, lane, keys.a[0], keys.b[0]);
  __syncthreads();

  f32x4 acc0[MT][4], acc1[MT][4], z_s[MT][4], hold[MT][4];

  // ---- encoder: h0 = x @ W_enc + b_enc ----
#pragma unroll
  for (int mtl = 0; mtl < MT; ++mtl) {
    int mb = (wave * MT + mtl) * 16 + qk * 4;
    f32x4 be = *(const f32x4*)&b_enc[mb];
#pragma unroll
    for (int nt = 0; nt < 4; ++nt) acc0[mtl][nt] = be;
  }
  gemm_pass<4, 1>(encf, nullptr, hp_s, wave, lane, acc0, acc1);
  __syncthreads();  // all x-plane reads done
#pragma unroll
  for (int mtl = 0; mtl < MT; ++mtl) {
    int mb = (wave * MT + mtl) * 16 + qk * 4;
    int kc = mb >> 5, hi2 = (mb >> 3) & 3, j0 = mb & 7, lp = ln + 16 * hi2;
#pragma unroll
    for (int nt = 0; nt < 4; ++nt) {
      f32x4 o = acc0[mtl][nt];
      hold[mtl][nt] = o;                 // h_old lives in registers from here on
      bh4 P0, P1, P2;
#pragma unroll
      for (int j = 0; j < 4; ++j) {
        float v = o[j];
        unsigned short h1 = f2bf(v);  float r1 = v - bf2f(h1);
        unsigned short h2 = f2bf(r1); float r2 = r1 - bf2f(h2);
        P0[j] = (short)h1; P1[j] = (short)h2; P2[j] = (short)f2bf(r2);
      }
      *(bh4*)&hp_s[HPS(0, kc, nt, lp, j0)] = P0;
      *(bh4*)&hp_s[HPS(1, kc, nt, lp, j0)] = P1;
      *(bh4*)&hp_s[HPS(2, kc, nt, lp, j0)] = P2;
    }
  }
  __syncthreads();

#pragma unroll 1
  for (int t = 0; t < TS; ++t) {
    // ---- fused z+r (C-init from pre tables incl. bias) ----
#pragma unroll
    for (int mtl = 0; mtl < MT; ++mtl) {
      int mb = (wave * MT + mtl) * 16 + qk * 4;
#pragma unroll
      for (int nt = 0; nt < 4; ++nt) {
        int code = (int)(state[nt * 16 + ln] & 7u);
        acc0[mtl][nt] = *(const f32x4*)&pre[(0 * 8 + code) * 256 + mb];
        acc1[mtl][nt] = *(const f32x4*)&pre[(1 * 8 + code) * 256 + mb];
      }
    }
    gemm_pass<8, 2>(zf, rf, hp_s, wave, lane, acc0, acc1);
    __syncthreads();  // all h-plane reads done
#pragma unroll
    for (int mtl = 0; mtl < MT; ++mtl) {
      int mb = (wave * MT + mtl) * 16 + qk * 4;
      int kc = mb >> 5, hi2 = (mb >> 3) & 3, j0 = mb & 7, lp = ln + 16 * hi2;
#pragma unroll
      for (int nt = 0; nt < 4; ++nt) {
        f32x4 ho = hold[mtl][nt];
        f32x4 zv;
        bh4 P0, P1, P2;
#pragma unroll
        for (int j = 0; j < 4; ++j) {
          zv[j] = sigf(acc0[mtl][nt][j]);
          float rhv = sigf(acc1[mtl][nt][j]) * ho[j];
          unsigned short h1 = f2bf(rhv); float r1 = rhv - bf2f(h1);
          unsigned short h2 = f2bf(r1);  float r2 = r1 - bf2f(h2);
          P0[j] = (short)h1; P1[j] = (short)h2; P2[j] = (short)f2bf(r2);
        }
        z_s[mtl][nt] = zv;
        *(bh4*)&hp_s[HPS(0, kc, nt, lp, j0)] = P0;
        *(bh4*)&hp_s[HPS(1, kc, nt, lp, j0)] = P1;
        *(bh4*)&hp_s[HPS(2, kc, nt, lp, j0)] = P2;
      }
    }
    __syncthreads();  // rh planes published

    // ---- candidate gate ----
#pragma unroll
    for (int mtl = 0; mtl < MT; ++mtl) {
      int mb = (wave * MT + mtl) * 16 + qk * 4;
#pragma unroll
      for (int nt = 0; nt < 4; ++nt) {
        int code = (int)(state[nt * 16 + ln] & 7u);
        acc0[mtl][nt] = *(const f32x4*)&pre[(2 * 8 + code) * 256 + mb];
      }
    }
    gemm_pass<8, 1>(hf, nullptr, hp_s, wave, lane, acc0, acc1);
    __syncthreads();  // all rh-plane reads done
#pragma unroll
    for (int mtl = 0; mtl < MT; ++mtl) {
      int mb = (wave * MT + mtl) * 16 + qk * 4;
      int kc = mb >> 5, hi2 = (mb >> 3) & 3, j0 = mb & 7, lp = ln + 16 * hi2;
#pragma unroll
      for (int nt = 0; nt < 4; ++nt) {
        f32x4 z = z_s[mtl][nt], ho = hold[mtl][nt], hn;
        bh4 P0, P1, P2;
#pragma unroll
        for (int j = 0; j < 4; ++j) {
          float ht = tanhf(acc0[mtl][nt][j]);
          hn[j] = (1.0f - z[j]) * ho[j] + z[j] * ht;
          unsigned short h1 = f2bf(hn[j]); float r1 = hn[j] - bf2f(h1);
          unsigned short h2 = f2bf(r1);    float r2 = r1 - bf2f(h2);
          P0[j] = (short)h1; P1[j] = (short)h2; P2[j] = (short)f2bf(r2);
        }
        hold[mtl][nt] = hn;              // persists to next step
        *(bh4*)&hp_s[HPS(0, kc, nt, lp, j0)] = P0;
        *(bh4*)&hp_s[HPS(1, kc, nt, lp, j0)] = P1;
        *(bh4*)&hp_s[HPS(2, kc, nt, lp, j0)] = P2;
      }
    }
    __syncthreads();  // h_new planes visible

    // ---- logits GEMM + sample (waves 0-3, nt=wave) || gumbel t+1 (waves 4-7) ----
    if (wave < 4) {
      f32x4 lacc;
#pragma unroll
      for (int j = 0; j < 4; ++j) lacc[j] = boutL[qk * 4 + j];
#pragma unroll 1
      for (int kc = 0; kc < 8; ++kc) {
        bfrag B0 = *(const bfrag*)&hp_s[HPS(0, kc, wave, lane, 0)];
        bfrag B1 = *(const bfrag*)&hp_s[HPS(1, kc, wave, lane, 0)];
        bfrag B2 = *(const bfrag*)&hp_s[HPS(2, kc, wave, lane, 0)];
        bfrag A[3];
#pragma unroll
        for (int p = 0; p < 3; ++p)
          A[p] = *(const bfrag*)(woutf + (p * 8 + kc) * 512 + lane * 8);
        lacc = prod6(A, B0, B1, B2, lacc);
      }
      // D[m=qk*4+j][n=ln]: vocab 0..3 at qk=0, vocab 4..5 at qk=1 regs 0..1
      float l4 = __shfl(lacc[0], ln + 16, 64);
      float l5 = __shfl(lacc[1], ln + 16, 64);
      if (qk == 0) {
        const int m = wave * 16 + ln;
        const int row = b0 + m;
        unsigned st = state[m];
        if (!(st & 8u)) {
          float l[VT] = {lacc[0], lacc[1], lacc[2], lacc[3], l4, l5};
          float best = 0.f; int tok = 0;
#pragma unroll
          for (int v = 0; v < VT; ++v) {
            float val = l[v] + gmb_s[((t & 1) * BM + m) * 6 + v];
            if (v == 0 || val > best) { best = val; tok = v; }
          }
          float lmax = l[0];
#pragma unroll
          for (int v = 1; v < VT; ++v) lmax = fmaxf(lmax, l[v]);
          float s = 0.f;
#pragma unroll
          for (int v = 0; v < VT; ++v) s += expf(l[v] - lmax);
          float lp = (l[tok] - lmax) - logf(s);
          tlp[m] += lp;
          const bool is_stop = (tok == VT - 1);
          unsigned len = ((st >> 4) & 7u) + (is_stop ? 0u : 1u);
#pragma unroll
          for (int v = 0; v < VT; ++v)
            out[(size_t)row * (TS * VT) + t * VT + v] = (v == tok) ? 1.0f : 0.0f;
          state[m] = (unsigned)tok | (is_stop ? 8u : 0u) | (len << 4);
        } else {
#pragma unroll
          for (int v = 0; v < VT; ++v)
            out[(size_t)row * (TS * VT) + t * VT + v] = 0.0f;
          state[m] = 6u | 8u | (st & 0x70u);
        }
      }
    } else if (t + 1 < TS) {
      gen_gumbel(gmb_s, t + 1, b0, wave - 4, lane, keys.a[t + 1], keys.b[t + 1]);
    }
    __syncthreads();  // state/tlp/gumbels visible for next step
  }

  if (tid < BM) {
    const int row = b0 + tid;
    out[(size_t)NB * (TS * VT) + row]      = tlp[tid];
    out[(size_t)NB * (TS * VT) + NB + row] = (float)((state[tid] >> 4) & 7u);
  }
}

extern "C" void kernel_launch(void* const* d_in, const int* in_sizes, int n_in,
                              void* d_out, int out_size, void* d_ws, size_t ws_size,
                              hipStream_t stream) {
  (void)in_sizes; (void)n_in; (void)out_size; (void)ws_size;
  const float* x          = (const float*)d_in[0];
  const float* W_enc      = (const float*)d_in[1];
  const float* b_enc      = (const float*)d_in[2];
  const float* W_embed    = (const float*)d_in[3];
  const float* b_embed    = (const float*)d_in[4];
  const float* W_z        = (const float*)d_in[5];
  const float* b_z        = (const float*)d_in[6];
  const float* W_r        = (const float*)d_in[7];
  const float* b_r        = (const float*)d_in[8];
  const float* W_h        = (const float*)d_in[9];
  const float* b_h        = (const float*)d_in[10];
  const float* W_out      = (const float*)d_in[11];
  const float* b_out      = (const float*)d_in[12];
  const float* start_embed= (const float*)d_in[13];
  float* out = (float*)d_out;

  // workspace: pre [0,24576); enc frags [24576,221184); z [221184,614400);
  // r [614400,1007616); h [1007616,1400832); wout frags [1400832,1425408)
  float* pre = (float*)d_ws;
  unsigned short* encf = (unsigned short*)((char*)d_ws + 24576);
  unsigned short* zfb  = (unsigned short*)((char*)d_ws + 221184);
  unsigned short* rfb  = (unsigned short*)((char*)d_ws + 614400);
  unsigned short* hfb  = (unsigned short*)((char*)d_ws + 1007616);
  unsigned short* wof  = (unsigned short*)((char*)d_ws + 1400832);

  pre_kernel<<<138, 256, 0, stream>>>(W_enc, W_embed, b_embed, start_embed,
                                      W_z, b_z, W_r, b_r, W_h, b_h, W_out,
                                      pre, encf, zfb, rfb, hfb, wof);

  // keys = jax.random.split(jax.random.key(42), 6), partitionable mode
  Keys K;
  for (int t = 0; t < 6; ++t) {
    uint32_t o0, o1;
    tf2x32(0u, 42u, 0u, (uint32_t)t, o0, o1);
    K.a[t] = o0; K.b[t] = o1;
  }

  main_kernel<<<NB / BM, NTH, 0, stream>>>(x, b_enc, b_out,
                                           pre, encf, zfb, rfb, hfb, wof, out, K);
}